// Round 7
// baseline (375.620 us; speedup 1.0000x reference)
//
#include <hip/hip_runtime.h>
#include <hip/hip_bf16.h>
#include <cstdint>
#include <cstddef>

// Problem constants
#define A_ 2
#define B_ 128
#define N_ 50000
#define D_ 512
#define E_ 4096
#define AB_ 256
#define CLIPV 1e-14f

// Workspace layout (float offsets)
static const size_t OFF_SYM   = 0;          // [AB_][N_] f32 symbolic; dead after k_enhagg -> outgemm partials
static const size_t OFF_SCORE = 12800000;   // [AB_][N_] p=exp(score); rows 0..127 overwritten in-place with agg f32
static const size_t OFF_TAIL  = 25600000;   // tail hi/lo bf16 (2 x 131072 ushort)
static const size_t OFF_STATS = 25731072;   // stats block (2048 floats)
// stats sub-offsets
#define ST_SYMSUM 0
#define ST_EXPSUM 512
#define ST_AGGSUM 1024
// out-gemm split-K geometry
#define CH_K 384
#define OCHUNK 131   // ceil(50000/384)

typedef __attribute__((ext_vector_type(8))) short short8;
typedef __attribute__((ext_vector_type(4))) float f32x4;

// round-to-nearest-even f32 -> bf16 bits
__device__ __forceinline__ unsigned short rne_bf16(float x) {
    unsigned int u = __float_as_uint(x);
    u += 0x7fffu + ((u >> 16) & 1u);
    return (unsigned short)(u >> 16);
}
__device__ __forceinline__ float bf16_to_f32(unsigned short b) {
    return __uint_as_float(((unsigned int)b) << 16);
}

// ---------------- tail = head + pred, split to bf16 hi/lo ----------------
__global__ __launch_bounds__(256) void k_tail(const float* __restrict__ head,
                                              const float* __restrict__ pred,
                                              unsigned short* __restrict__ tail_hi,
                                              unsigned short* __restrict__ tail_lo) {
    int i = blockIdx.x * 256 + threadIdx.x;
    if (i < AB_ * D_) {
        float t = head[i] + pred[i];
        unsigned short hb = rne_bf16(t);
        float hf = bf16_to_f32(hb);
        unsigned short lb = rne_bf16(t - hf);
        tail_hi[i] = hb;
        tail_lo[i] = lb;
    }
}

// ---------------- scatter-add symbolic ----------------
__global__ __launch_bounds__(256) void k_scatter(const float* __restrict__ hv,
                                                 const float* __restrict__ ev,
                                                 const int* __restrict__ es,
                                                 const int* __restrict__ ed,
                                                 float* __restrict__ sym) {
    int ab = blockIdx.x;
    const float* hvr = hv + (size_t)ab * N_;
    float* symr = sym + (size_t)ab * N_;
    int base = ab * E_;
    for (int e = threadIdx.x; e < E_; e += 256) {
        float v = ev[base + e];
        int s = es[base + e];
        int d = ed[base + e];
        atomicAdd(&symr[d], v * hvr[s]);
    }
}

// ---------------- masked sym row-sums ----------------
__global__ __launch_bounds__(256) void k_symsum(const float* __restrict__ sym,
                                                float* __restrict__ stats) {
    int ab = blockIdx.x >> 2, part = blockIdx.x & 3;
    const float4* src = reinterpret_cast<const float4*>(sym + (size_t)ab * N_ + part * 12500);
    float s = 0.f;
    for (int i = threadIdx.x; i < 3125; i += 256) {
        float4 v = src[i];
        s += ((v.x < CLIPV) ? 0.f : v.x) + ((v.y < CLIPV) ? 0.f : v.y)
           + ((v.z < CLIPV) ? 0.f : v.z) + ((v.w < CLIPV) ? 0.f : v.w);
    }
    __shared__ float red[256];
    red[threadIdx.x] = s;
    __syncthreads();
    for (int st = 128; st > 0; st >>= 1) {
        if (threadIdx.x < st) red[threadIdx.x] += red[threadIdx.x + st];
        __syncthreads();
    }
    if (threadIdx.x == 0) atomicAdd(&stats[ST_SYMSUM + ab], red[0]);
}

// ---------------- score GEMM (split-bf16 MFMA), R3-style 2-barrier, high-TLP, fused exp ----------------
// Block: 128 m x 64 n, 4 waves (2m x 2n wave-grid, wave tile 64x32), BK=32, single buffer 30 KB
// -> 5 blocks/CU. Grid 1568 (98 chunks of 16) with pair-local XCD swizzle: both m-halves of an
// n-strip land on the same XCD (shared ent rows -> one L2 fill).
#define S2A_HI 0
#define S2A_LO 5120
#define S2B_HI 10240
#define S2B_LO 12800
#define S2PITCH 40

__global__ __launch_bounds__(256) void k_score(const float* __restrict__ ent,
                                               const unsigned short* __restrict__ tail_hi,
                                               const unsigned short* __restrict__ tail_lo,
                                               float* __restrict__ p_out,
                                               float* __restrict__ stats) {
    // swizzle decode: chunk of 16 blocks = 8 n-strips x 2 m-halves; member p differs by 8
    // -> same XCD (dispatch id % 8) for both m-halves of a strip.
    int bid = blockIdx.x;
    int chunk = bid >> 4, r = bid & 15;
    int nt = chunk * 8 + (r & 7);
    int mt = r >> 3;
    if (nt >= 782) return;
    const int n0 = nt * 64;
    const int m0 = mt * 128;

    __shared__ unsigned short lds[15360];   // 30 KB
    const int tid = threadIdx.x;
    const int w = tid >> 6;
    const int l = tid & 63;
    const int lm = l & 15;
    const int kg = l >> 4;
    const int wm = w >> 1;         // wave m-half (64 rows)
    const int wn = w & 1;          // wave n-half (32 cols)

    f32x4 acc[4][2];
    #pragma unroll
    for (int i = 0; i < 4; ++i)
        #pragma unroll
        for (int j = 0; j < 2; ++j) acc[i][j] = (f32x4){0.f, 0.f, 0.f, 0.f};

    // A staging role: row ar = tid>>1 (0..127), k-half h (16 ushorts)
    const int ar = tid >> 1;
    const int ah2 = tid & 1;
    const unsigned short* gAh = tail_hi + (size_t)(m0 + ar) * D_ + ah2 * 16;
    const unsigned short* gAl = tail_lo + (size_t)(m0 + ar) * D_ + ah2 * 16;
    // B staging role: n-row bn = tid>>2 (0..63), chunk bc = tid&3 (8 floats)
    const int bn = tid >> 2;
    const int bc = tid & 3;
    int entrow = n0 + bn;
    if (entrow > N_ - 1) entrow = N_ - 1;
    const float* entp = ent + (size_t)entrow * D_ + bc * 8;

    // staging registers
    short8 rh0, rh1, rl0, rl1;
    float4 rb0, rb1;

    // prologue: load tile 0, write, sync
    rh0 = *reinterpret_cast<const short8*>(gAh);
    rh1 = *reinterpret_cast<const short8*>(gAh + 8);
    rl0 = *reinterpret_cast<const short8*>(gAl);
    rl1 = *reinterpret_cast<const short8*>(gAl + 8);
    rb0 = *reinterpret_cast<const float4*>(entp);
    rb1 = *reinterpret_cast<const float4*>(entp + 4);
    {
        *reinterpret_cast<short8*>(&lds[S2A_HI + ar * S2PITCH + ah2 * 16]) = rh0;
        *reinterpret_cast<short8*>(&lds[S2A_HI + ar * S2PITCH + ah2 * 16 + 8]) = rh1;
        *reinterpret_cast<short8*>(&lds[S2A_LO + ar * S2PITCH + ah2 * 16]) = rl0;
        *reinterpret_cast<short8*>(&lds[S2A_LO + ar * S2PITCH + ah2 * 16 + 8]) = rl1;
        float f[8] = {rb0.x, rb0.y, rb0.z, rb0.w, rb1.x, rb1.y, rb1.z, rb1.w};
        short8 hb, lb;
        #pragma unroll
        for (int j = 0; j < 8; ++j) {
            unsigned short h = rne_bf16(f[j]);
            hb[j] = (short)h;
            lb[j] = (short)rne_bf16(f[j] - bf16_to_f32(h));
        }
        *reinterpret_cast<short8*>(&lds[S2B_HI + bn * S2PITCH + bc * 8]) = hb;
        *reinterpret_cast<short8*>(&lds[S2B_LO + bn * S2PITCH + bc * 8]) = lb;
    }
    __syncthreads();

    for (int t = 0; t < 16; ++t) {
        // issue next-tile global loads (drain at the mid-iter barrier, under MFMA)
        if (t < 15) {
            const int k1 = (t + 1) * 32;
            rh0 = *reinterpret_cast<const short8*>(gAh + k1);
            rh1 = *reinterpret_cast<const short8*>(gAh + k1 + 8);
            rl0 = *reinterpret_cast<const short8*>(gAl + k1);
            rl1 = *reinterpret_cast<const short8*>(gAl + k1 + 8);
            rb0 = *reinterpret_cast<const float4*>(entp + k1);
            rb1 = *reinterpret_cast<const float4*>(entp + k1 + 4);
        }
        // MFMA on tile t
        short8 bh[2], bl[2];
        #pragma unroll
        for (int nj = 0; nj < 2; ++nj) {
            int br = wn * 32 + nj * 16 + lm;
            bh[nj] = *reinterpret_cast<const short8*>(&lds[S2B_HI + br * S2PITCH + kg * 8]);
            bl[nj] = *reinterpret_cast<const short8*>(&lds[S2B_LO + br * S2PITCH + kg * 8]);
        }
        #pragma unroll
        for (int mi = 0; mi < 4; ++mi) {
            int arr = wm * 64 + mi * 16 + lm;
            short8 ah = *reinterpret_cast<const short8*>(&lds[S2A_HI + arr * S2PITCH + kg * 8]);
            short8 al = *reinterpret_cast<const short8*>(&lds[S2A_LO + arr * S2PITCH + kg * 8]);
            #pragma unroll
            for (int nj = 0; nj < 2; ++nj) {
                acc[mi][nj] = __builtin_amdgcn_mfma_f32_16x16x32_bf16(ah, bh[nj], acc[mi][nj], 0, 0, 0);
                acc[mi][nj] = __builtin_amdgcn_mfma_f32_16x16x32_bf16(ah, bl[nj], acc[mi][nj], 0, 0, 0);
                acc[mi][nj] = __builtin_amdgcn_mfma_f32_16x16x32_bf16(al, bh[nj], acc[mi][nj], 0, 0, 0);
            }
        }
        if (t < 15) {
            __syncthreads();
            // write tile t+1 from regs
            *reinterpret_cast<short8*>(&lds[S2A_HI + ar * S2PITCH + ah2 * 16]) = rh0;
            *reinterpret_cast<short8*>(&lds[S2A_HI + ar * S2PITCH + ah2 * 16 + 8]) = rh1;
            *reinterpret_cast<short8*>(&lds[S2A_LO + ar * S2PITCH + ah2 * 16]) = rl0;
            *reinterpret_cast<short8*>(&lds[S2A_LO + ar * S2PITCH + ah2 * 16 + 8]) = rl1;
            float f[8] = {rb0.x, rb0.y, rb0.z, rb0.w, rb1.x, rb1.y, rb1.z, rb1.w};
            short8 hb, lb;
            #pragma unroll
            for (int j = 0; j < 8; ++j) {
                unsigned short h = rne_bf16(f[j]);
                hb[j] = (short)h;
                lb[j] = (short)rne_bf16(f[j] - bf16_to_f32(h));
            }
            *reinterpret_cast<short8*>(&lds[S2B_HI + bn * S2PITCH + bc * 8]) = hb;
            *reinterpret_cast<short8*>(&lds[S2B_LO + bn * S2PITCH + bc * 8]) = lb;
            __syncthreads();
        }
    }

    // epilogue: p = exp(score) (no max-sub; scores are small), store + per-row expsum
    #pragma unroll
    for (int mi = 0; mi < 4; ++mi) {
        #pragma unroll
        for (int j = 0; j < 4; ++j) {
            int row = m0 + wm * 64 + mi * 16 + kg * 4 + j;
            float rsum = 0.f;
            #pragma unroll
            for (int nj = 0; nj < 2; ++nj) {
                int col = n0 + wn * 32 + nj * 16 + lm;
                if (col < N_) {
                    float pv = expf(acc[mi][nj][j]);
                    p_out[(size_t)row * N_ + col] = pv;
                    rsum += pv;
                }
            }
            rsum += __shfl_xor(rsum, 1);
            rsum += __shfl_xor(rsum, 2);
            rsum += __shfl_xor(rsum, 4);
            rsum += __shfl_xor(rsum, 8);
            if (lm == 0) atomicAdd(&stats[ST_EXPSUM + row], rsum);
        }
    }
}

// ---------------- fused enhance + product + aggsum; agg f32 written IN PLACE over p rows 0..127 ----------------
__global__ __launch_bounds__(256) void k_enhagg(float* __restrict__ p,
                                                const float* __restrict__ sym,
                                                float* __restrict__ stats) {
    int b = blockIdx.x >> 2, part = blockIdx.x & 3;
    size_t off0 = (size_t)b * N_ + part * 12500;
    size_t off1 = (size_t)(128 + b) * N_ + part * 12500;
    float is0 = 1.f / fmaxf(CLIPV, stats[ST_SYMSUM + b]);
    float is1 = 1.f / fmaxf(CLIPV, stats[ST_SYMSUM + 128 + b]);
    float ie0 = 1.f / fmaxf(CLIPV, stats[ST_EXPSUM + b]);
    float ie1 = 1.f / fmaxf(CLIPV, stats[ST_EXPSUM + 128 + b]);
    const float4* s0p = reinterpret_cast<const float4*>(sym + off0);
    const float4* s1p = reinterpret_cast<const float4*>(sym + off1);
    float4* p0p = reinterpret_cast<float4*>(p + off0);
    const float4* p1p = reinterpret_cast<const float4*>(p + off1);
    float local = 0.f;
    for (int i = threadIdx.x; i < 3125; i += 256) {
        float4 s0 = s0p[i], s1 = s1p[i], q0 = p0p[i], q1 = p1p[i];
        float sv0[4] = {s0.x, s0.y, s0.z, s0.w};
        float sv1[4] = {s1.x, s1.y, s1.z, s1.w};
        float qv0[4] = {q0.x, q0.y, q0.z, q0.w};
        float qv1[4] = {q1.x, q1.y, q1.z, q1.w};
        float vv[4];
        #pragma unroll
        for (int c = 0; c < 4; ++c) {
            float a0 = (sv0[c] < CLIPV) ? 0.f : sv0[c];
            float a1 = (sv1[c] < CLIPV) ? 0.f : sv1[c];
            float e0 = a0 * is0 + qv0[c] * ie0; e0 = (e0 < CLIPV) ? 0.f : e0;
            float e1 = a1 * is1 + qv1[c] * ie1; e1 = (e1 < CLIPV) ? 0.f : e1;
            float v = e0 * e1 * 0.25f;
            v = (v < CLIPV) ? 0.f : v;
            local += v;
            vv[c] = v;
        }
        float4 o; o.x = vv[0]; o.y = vv[1]; o.z = vv[2]; o.w = vv[3];
        p0p[i] = o;
    }
    __shared__ float red[256];
    red[threadIdx.x] = local;
    __syncthreads();
    for (int st = 128; st > 0; st >>= 1) {
        if (threadIdx.x < st) red[threadIdx.x] += red[threadIdx.x + st];
        __syncthreads();
    }
    if (threadIdx.x == 0) atomicAdd(&stats[ST_AGGSUM + b], red[0]);
}

// ---------------- out GEMM via split-bf16 MFMA, split-K, double-buffered, 1 barrier/K-step ----------------
#define APITCH 40
#define OG_BUF 20480
#define OLDS_A_HI 0
#define OLDS_A_LO 5120
#define OLDS_B_HI 10240
#define OLDS_B_LO 15360

__global__ __launch_bounds__(256) void k_outgemm(const float* __restrict__ ent,
                                                 const float* __restrict__ aggf,
                                                 float* __restrict__ part) {
    __shared__ unsigned short lds[40960];   // 80 KB: 2 buffers
    const int bid = blockIdx.x;
    const int chunk = bid >> 2, dt = bid & 3;
    const int n0 = chunk * CH_K, d0 = dt * 128;
    const int tid = threadIdx.x;
    const int w = tid >> 6;
    const int l = tid & 63;
    const int lm = l & 15;
    const int kg = l >> 4;
    const int m0w = (w >> 1) * 64;
    const int c0w = (w & 1) * 64;

    f32x4 acc[4][4];
    #pragma unroll
    for (int i = 0; i < 4; ++i)
        #pragma unroll
        for (int j = 0; j < 4; ++j) acc[i][j] = (f32x4){0.f, 0.f, 0.f, 0.f};

    const int arow = tid >> 1;
    const int ahalf = tid & 1;
    const int dcol = tid & 127;
    const int bhalf = tid >> 7;
    const size_t entcol = (size_t)(d0 + dcol);

    float ra[16], rb[16];

    auto loadA = [&](int k0) {
        int nbase = n0 + k0 + ahalf * 16;
        const float* asrc = aggf + (size_t)arow * N_ + nbase;
        #pragma unroll
        for (int c = 0; c < 2; ++c) {
            if (nbase + c * 8 + 7 < N_) {
                float4 f0 = *reinterpret_cast<const float4*>(asrc + c * 8);
                float4 f1 = *reinterpret_cast<const float4*>(asrc + c * 8 + 4);
                ra[c*8+0]=f0.x; ra[c*8+1]=f0.y; ra[c*8+2]=f0.z; ra[c*8+3]=f0.w;
                ra[c*8+4]=f1.x; ra[c*8+5]=f1.y; ra[c*8+6]=f1.z; ra[c*8+7]=f1.w;
            } else {
                #pragma unroll
                for (int j = 0; j < 8; ++j) {
                    int n = nbase + c * 8 + j;
                    ra[c*8+j] = (n < N_) ? aggf[(size_t)arow * N_ + n] : 0.f;
                }
            }
        }
    };
    auto loadB = [&](int k0) {
        int nb = n0 + k0 + bhalf * 16;
        #pragma unroll
        for (int j = 0; j < 16; ++j) {
            int n = nb + j;
            if (n > N_ - 1) n = N_ - 1;
            rb[j] = ent[(size_t)n * D_ + entcol];
        }
    };
    auto stage = [&](int bufbase) {
        #pragma unroll
        for (int c = 0; c < 2; ++c) {
            short8 hb, lb;
            #pragma unroll
            for (int j = 0; j < 8; ++j) {
                float f = ra[c*8+j];
                unsigned short h = rne_bf16(f);
                hb[j] = (short)h;
                lb[j] = (short)rne_bf16(f - bf16_to_f32(h));
            }
            *reinterpret_cast<short8*>(&lds[bufbase + OLDS_A_HI + arow * APITCH + ahalf * 16 + c * 8]) = hb;
            *reinterpret_cast<short8*>(&lds[bufbase + OLDS_A_LO + arow * APITCH + ahalf * 16 + c * 8]) = lb;
        }
        #pragma unroll
        for (int c = 0; c < 2; ++c) {
            short8 hb, lb;
            #pragma unroll
            for (int j = 0; j < 8; ++j) {
                float f = rb[c*8+j];
                unsigned short h = rne_bf16(f);
                hb[j] = (short)h;
                lb[j] = (short)rne_bf16(f - bf16_to_f32(h));
            }
            *reinterpret_cast<short8*>(&lds[bufbase + OLDS_B_HI + dcol * APITCH + bhalf * 16 + c * 8]) = hb;
            *reinterpret_cast<short8*>(&lds[bufbase + OLDS_B_LO + dcol * APITCH + bhalf * 16 + c * 8]) = lb;
        }
    };

    // prologue: stage tile 0, prefetch regs for tile 1
    loadA(0); loadB(0);
    stage(0);
    loadA(32); loadB(32);
    __syncthreads();

    for (int t = 0; t < 12; ++t) {
        const int base = (t & 1) * OG_BUF;
        const int nb2 = ((t + 1) & 1) * OG_BUF;
        if (t < 11) stage(nb2);                       // regs hold tile t+1
        if (t < 10) { loadA((t + 2) * 32); loadB((t + 2) * 32); }
        short8 ah[4], al[4], bh[4], bl[4];
        #pragma unroll
        for (int mi = 0; mi < 4; ++mi) {
            int r = m0w + mi * 16 + lm;
            ah[mi] = *reinterpret_cast<const short8*>(&lds[base + OLDS_A_HI + r * APITCH + kg * 8]);
            al[mi] = *reinterpret_cast<const short8*>(&lds[base + OLDS_A_LO + r * APITCH + kg * 8]);
        }
        #pragma unroll
        for (int nj = 0; nj < 4; ++nj) {
            int r = c0w + nj * 16 + lm;
            bh[nj] = *reinterpret_cast<const short8*>(&lds[base + OLDS_B_HI + r * APITCH + kg * 8]);
            bl[nj] = *reinterpret_cast<const short8*>(&lds[base + OLDS_B_LO + r * APITCH + kg * 8]);
        }
        #pragma unroll
        for (int mi = 0; mi < 4; ++mi)
            #pragma unroll
            for (int nj = 0; nj < 4; ++nj) {
                acc[mi][nj] = __builtin_amdgcn_mfma_f32_16x16x32_bf16(ah[mi], bh[nj], acc[mi][nj], 0, 0, 0);
                acc[mi][nj] = __builtin_amdgcn_mfma_f32_16x16x32_bf16(ah[mi], bl[nj], acc[mi][nj], 0, 0, 0);
                acc[mi][nj] = __builtin_amdgcn_mfma_f32_16x16x32_bf16(al[mi], bh[nj], acc[mi][nj], 0, 0, 0);
            }
        __syncthreads();
    }

    float* pbase = part + (size_t)chunk * 65536;
    #pragma unroll
    for (int nj = 0; nj < 4; ++nj) {
        int dcolo = d0 + c0w + nj * 16 + lm;
        #pragma unroll
        for (int mi = 0; mi < 4; ++mi) {
            int brow = m0w + mi * 16 + kg * 4;
            #pragma unroll
            for (int j = 0; j < 4; ++j)
                pbase[(size_t)(brow + j) * 512 + dcolo] = acc[mi][nj][j];
        }
    }
}

// ---------------- reduce partials + normalize by agg_sum ----------------
__global__ __launch_bounds__(256) void k_redout(const float* __restrict__ part,
                                                const float* __restrict__ stats,
                                                float* __restrict__ out) {
    int i = blockIdx.x * 256 + threadIdx.x;  // 0..65535
    int b = i >> 9;
    float s = 0.f;
    for (int c = 0; c < OCHUNK; ++c) s += part[(size_t)c * 65536 + i];
    out[i] = s / fmaxf(CLIPV, stats[ST_AGGSUM + b]);
}

extern "C" void kernel_launch(void* const* d_in, const int* in_sizes, int n_in,
                              void* d_out, int out_size, void* d_ws, size_t ws_size,
                              hipStream_t stream) {
    const float* ent = (const float*)d_in[0];
    const float* hv  = (const float*)d_in[1];
    const float* he  = (const float*)d_in[2];
    const float* pe  = (const float*)d_in[3];
    const float* ev  = (const float*)d_in[4];
    const int*   es  = (const int*)d_in[5];
    const int*   ed  = (const int*)d_in[6];
    float* out = (float*)d_out;
    float* ws = (float*)d_ws;

    unsigned short* tail_hi = (unsigned short*)(ws + OFF_TAIL);
    unsigned short* tail_lo = tail_hi + (size_t)AB_ * D_;

    hipMemsetAsync(ws + OFF_SYM, 0, (size_t)AB_ * N_ * sizeof(float), stream);
    hipMemsetAsync(ws + OFF_STATS, 0, 2048 * sizeof(float), stream);

    k_tail<<<512, 256, 0, stream>>>(he, pe, tail_hi, tail_lo);
    k_scatter<<<AB_, 256, 0, stream>>>(hv, ev, es, ed, ws + OFF_SYM);
    k_score<<<1568, 256, 0, stream>>>(ent, tail_hi, tail_lo, ws + OFF_SCORE, ws + OFF_STATS);
    k_symsum<<<AB_ * 4, 256, 0, stream>>>(ws + OFF_SYM, ws + OFF_STATS);
    k_enhagg<<<B_ * 4, 256, 0, stream>>>(ws + OFF_SCORE, ws + OFF_SYM, ws + OFF_STATS);
    k_outgemm<<<OCHUNK * 4, 256, 0, stream>>>(ent, ws + OFF_SCORE, ws + OFF_SYM);
    k_redout<<<256, 256, 0, stream>>>(ws + OFF_SYM, ws + OFF_STATS, out);
}

// Round 8
// 358.975 us; speedup vs baseline: 1.0464x; 1.0464x over previous
//
#include <hip/hip_runtime.h>
#include <hip/hip_bf16.h>
#include <cstdint>
#include <cstddef>

// Problem constants
#define A_ 2
#define B_ 128
#define N_ 50000
#define D_ 512
#define E_ 4096
#define AB_ 256
#define CLIPV 1e-14f

// Workspace layout (float offsets)
static const size_t OFF_SYM   = 0;          // [AB_][N_] f32 symbolic; dead after k_enhagg -> outgemm partials
static const size_t OFF_SCORE = 12800000;   // [AB_][N_] p=exp(score); rows 0..127 overwritten in-place with agg f32
static const size_t OFF_TAIL  = 25600000;   // tail hi/lo bf16 (2 x 131072 ushort)
static const size_t OFF_STATS = 25731072;   // stats block (2048 floats)
// stats sub-offsets
#define ST_SYMSUM 0
#define ST_EXPSUM 512
#define ST_AGGSUM 1024
// out-gemm split-K geometry
#define CH_K 384
#define OCHUNK 131   // ceil(50000/384)

typedef __attribute__((ext_vector_type(8))) short short8;
typedef __attribute__((ext_vector_type(4))) float f32x4;

// round-to-nearest-even f32 -> bf16 bits
__device__ __forceinline__ unsigned short rne_bf16(float x) {
    unsigned int u = __float_as_uint(x);
    u += 0x7fffu + ((u >> 16) & 1u);
    return (unsigned short)(u >> 16);
}
__device__ __forceinline__ float bf16_to_f32(unsigned short b) {
    return __uint_as_float(((unsigned int)b) << 16);
}
__device__ __forceinline__ void cvt8(const float4& a, const float4& b, short8& hb, short8& lb) {
    float f[8] = {a.x, a.y, a.z, a.w, b.x, b.y, b.z, b.w};
    #pragma unroll
    for (int j = 0; j < 8; ++j) {
        unsigned short h = rne_bf16(f[j]);
        hb[j] = (short)h;
        lb[j] = (short)rne_bf16(f[j] - bf16_to_f32(h));
    }
}

// ---------------- tail = head + pred, split to bf16 hi/lo ----------------
__global__ __launch_bounds__(256) void k_tail(const float* __restrict__ head,
                                              const float* __restrict__ pred,
                                              unsigned short* __restrict__ tail_hi,
                                              unsigned short* __restrict__ tail_lo) {
    int i = blockIdx.x * 256 + threadIdx.x;
    if (i < AB_ * D_) {
        float t = head[i] + pred[i];
        unsigned short hb = rne_bf16(t);
        float hf = bf16_to_f32(hb);
        unsigned short lb = rne_bf16(t - hf);
        tail_hi[i] = hb;
        tail_lo[i] = lb;
    }
}

// ---------------- scatter-add symbolic ----------------
__global__ __launch_bounds__(256) void k_scatter(const float* __restrict__ hv,
                                                 const float* __restrict__ ev,
                                                 const int* __restrict__ es,
                                                 const int* __restrict__ ed,
                                                 float* __restrict__ sym) {
    int ab = blockIdx.x;
    const float* hvr = hv + (size_t)ab * N_;
    float* symr = sym + (size_t)ab * N_;
    int base = ab * E_;
    for (int e = threadIdx.x; e < E_; e += 256) {
        float v = ev[base + e];
        int s = es[base + e];
        int d = ed[base + e];
        atomicAdd(&symr[d], v * hvr[s]);
    }
}

// ---------------- masked sym row-sums ----------------
__global__ __launch_bounds__(256) void k_symsum(const float* __restrict__ sym,
                                                float* __restrict__ stats) {
    int ab = blockIdx.x >> 2, part = blockIdx.x & 3;
    const float4* src = reinterpret_cast<const float4*>(sym + (size_t)ab * N_ + part * 12500);
    float s = 0.f;
    for (int i = threadIdx.x; i < 3125; i += 256) {
        float4 v = src[i];
        s += ((v.x < CLIPV) ? 0.f : v.x) + ((v.y < CLIPV) ? 0.f : v.y)
           + ((v.z < CLIPV) ? 0.f : v.z) + ((v.w < CLIPV) ? 0.f : v.w);
    }
    __shared__ float red[256];
    red[threadIdx.x] = s;
    __syncthreads();
    for (int st = 128; st > 0; st >>= 1) {
        if (threadIdx.x < st) red[threadIdx.x] += red[threadIdx.x + st];
        __syncthreads();
    }
    if (threadIdx.x == 0) atomicAdd(&stats[ST_SYMSUM + ab], red[0]);
}

// ---------------- score GEMM: LDS-free, barrier-free, per-wave frag loads ----------------
// Block: 256 m x 64 n, 4 waves (wave tile 64x64). No LDS, no __syncthreads.
// A (tail) is already bf16 hi/lo in global -> direct short8 frag loads (L2-hot, 512 KB).
// B (ent) f32 loaded 1 K-step ahead into regs, converted to hi/lo in-register.
// The 4 waves read the same ent strip -> served by the XCD L2 after first touch.
__global__ __launch_bounds__(256, 2) void k_score(const float* __restrict__ ent,
                                                  const unsigned short* __restrict__ tail_hi,
                                                  const unsigned short* __restrict__ tail_lo,
                                                  float* __restrict__ p_out,
                                                  float* __restrict__ stats) {
    const int tid = threadIdx.x;
    const int w = tid >> 6;
    const int l = tid & 63;
    const int lm = l & 15;
    const int kg = l >> 4;
    const int n0 = blockIdx.x * 64;
    const int m0w = w * 64;

    f32x4 acc[4][4];
    #pragma unroll
    for (int i = 0; i < 4; ++i)
        #pragma unroll
        for (int j = 0; j < 4; ++j) acc[i][j] = (f32x4){0.f, 0.f, 0.f, 0.f};

    // 32-bit offsets (SGPR base + VGPR offset addressing)
    int oA[4], oB[4];
    #pragma unroll
    for (int mi = 0; mi < 4; ++mi)
        oA[mi] = (m0w + mi * 16 + lm) * D_ + kg * 8;
    #pragma unroll
    for (int nj = 0; nj < 4; ++nj) {
        int col = n0 + nj * 16 + lm;
        if (col > N_ - 1) col = N_ - 1;
        oB[nj] = col * D_ + kg * 8;
    }

    // B f32 regs for current step (prologue: k=0)
    float4 f0[4], f1[4];
    #pragma unroll
    for (int nj = 0; nj < 4; ++nj) {
        f0[nj] = *reinterpret_cast<const float4*>(&ent[oB[nj]]);
        f1[nj] = *reinterpret_cast<const float4*>(&ent[oB[nj] + 4]);
    }

    #pragma unroll 2
    for (int t = 0; t < 16; ++t) {
        const int k0 = t * 32;
        // A frags for this step (L2-hot, covered by the convert below)
        short8 ah[4], al[4];
        #pragma unroll
        for (int mi = 0; mi < 4; ++mi) {
            ah[mi] = *reinterpret_cast<const short8*>(&tail_hi[oA[mi] + k0]);
            al[mi] = *reinterpret_cast<const short8*>(&tail_lo[oA[mi] + k0]);
        }
        // issue next-step B loads (in flight across convert + MFMA)
        float4 f0n[4], f1n[4];
        if (t < 15) {
            const int k1 = k0 + 32;
            #pragma unroll
            for (int nj = 0; nj < 4; ++nj) {
                f0n[nj] = *reinterpret_cast<const float4*>(&ent[oB[nj] + k1]);
                f1n[nj] = *reinterpret_cast<const float4*>(&ent[oB[nj] + k1 + 4]);
            }
        }
        // convert current B to hi/lo
        short8 bh[4], bl[4];
        #pragma unroll
        for (int nj = 0; nj < 4; ++nj) cvt8(f0[nj], f1[nj], bh[nj], bl[nj]);
        // 48 MFMA
        #pragma unroll
        for (int mi = 0; mi < 4; ++mi)
            #pragma unroll
            for (int nj = 0; nj < 4; ++nj) {
                acc[mi][nj] = __builtin_amdgcn_mfma_f32_16x16x32_bf16(ah[mi], bh[nj], acc[mi][nj], 0, 0, 0);
                acc[mi][nj] = __builtin_amdgcn_mfma_f32_16x16x32_bf16(ah[mi], bl[nj], acc[mi][nj], 0, 0, 0);
                acc[mi][nj] = __builtin_amdgcn_mfma_f32_16x16x32_bf16(al[mi], bh[nj], acc[mi][nj], 0, 0, 0);
            }
        if (t < 15) {
            #pragma unroll
            for (int nj = 0; nj < 4; ++nj) { f0[nj] = f0n[nj]; f1[nj] = f1n[nj]; }
        }
    }

    // epilogue: p = exp(score) (no max-sub; scores are small), store + per-row expsum
    #pragma unroll
    for (int mi = 0; mi < 4; ++mi) {
        #pragma unroll
        for (int j = 0; j < 4; ++j) {
            int row = m0w + mi * 16 + kg * 4 + j;
            float rsum = 0.f;
            #pragma unroll
            for (int nj = 0; nj < 4; ++nj) {
                int col = n0 + nj * 16 + lm;
                if (col < N_) {
                    float pv = expf(acc[mi][nj][j]);
                    p_out[(size_t)row * N_ + col] = pv;
                    rsum += pv;
                }
            }
            rsum += __shfl_xor(rsum, 1);
            rsum += __shfl_xor(rsum, 2);
            rsum += __shfl_xor(rsum, 4);
            rsum += __shfl_xor(rsum, 8);
            if (lm == 0) atomicAdd(&stats[ST_EXPSUM + row], rsum);
        }
    }
}

// ---------------- fused enhance + product + aggsum; agg f32 written IN PLACE over p rows 0..127 ----------------
__global__ __launch_bounds__(256) void k_enhagg(float* __restrict__ p,
                                                const float* __restrict__ sym,
                                                float* __restrict__ stats) {
    int b = blockIdx.x >> 2, part = blockIdx.x & 3;
    size_t off0 = (size_t)b * N_ + part * 12500;
    size_t off1 = (size_t)(128 + b) * N_ + part * 12500;
    float is0 = 1.f / fmaxf(CLIPV, stats[ST_SYMSUM + b]);
    float is1 = 1.f / fmaxf(CLIPV, stats[ST_SYMSUM + 128 + b]);
    float ie0 = 1.f / fmaxf(CLIPV, stats[ST_EXPSUM + b]);
    float ie1 = 1.f / fmaxf(CLIPV, stats[ST_EXPSUM + 128 + b]);
    const float4* s0p = reinterpret_cast<const float4*>(sym + off0);
    const float4* s1p = reinterpret_cast<const float4*>(sym + off1);
    float4* p0p = reinterpret_cast<float4*>(p + off0);
    const float4* p1p = reinterpret_cast<const float4*>(p + off1);
    float local = 0.f;
    for (int i = threadIdx.x; i < 3125; i += 256) {
        float4 s0 = s0p[i], s1 = s1p[i], q0 = p0p[i], q1 = p1p[i];
        float sv0[4] = {s0.x, s0.y, s0.z, s0.w};
        float sv1[4] = {s1.x, s1.y, s1.z, s1.w};
        float qv0[4] = {q0.x, q0.y, q0.z, q0.w};
        float qv1[4] = {q1.x, q1.y, q1.z, q1.w};
        float vv[4];
        #pragma unroll
        for (int c = 0; c < 4; ++c) {
            float a0 = (sv0[c] < CLIPV) ? 0.f : sv0[c];
            float a1 = (sv1[c] < CLIPV) ? 0.f : sv1[c];
            float e0 = a0 * is0 + qv0[c] * ie0; e0 = (e0 < CLIPV) ? 0.f : e0;
            float e1 = a1 * is1 + qv1[c] * ie1; e1 = (e1 < CLIPV) ? 0.f : e1;
            float v = e0 * e1 * 0.25f;
            v = (v < CLIPV) ? 0.f : v;
            local += v;
            vv[c] = v;
        }
        float4 o; o.x = vv[0]; o.y = vv[1]; o.z = vv[2]; o.w = vv[3];
        p0p[i] = o;
    }
    __shared__ float red[256];
    red[threadIdx.x] = local;
    __syncthreads();
    for (int st = 128; st > 0; st >>= 1) {
        if (threadIdx.x < st) red[threadIdx.x] += red[threadIdx.x + st];
        __syncthreads();
    }
    if (threadIdx.x == 0) atomicAdd(&stats[ST_AGGSUM + b], red[0]);
}

// ---------------- out GEMM via split-bf16 MFMA, split-K, double-buffered, 1 barrier/K-step ----------------
#define APITCH 40
#define OG_BUF 20480
#define OLDS_A_HI 0
#define OLDS_A_LO 5120
#define OLDS_B_HI 10240
#define OLDS_B_LO 15360

__global__ __launch_bounds__(256) void k_outgemm(const float* __restrict__ ent,
                                                 const float* __restrict__ aggf,
                                                 float* __restrict__ part) {
    __shared__ unsigned short lds[40960];   // 80 KB: 2 buffers
    const int bid = blockIdx.x;
    const int chunk = bid >> 2, dt = bid & 3;
    const int n0 = chunk * CH_K, d0 = dt * 128;
    const int tid = threadIdx.x;
    const int w = tid >> 6;
    const int l = tid & 63;
    const int lm = l & 15;
    const int kg = l >> 4;
    const int m0w = (w >> 1) * 64;
    const int c0w = (w & 1) * 64;

    f32x4 acc[4][4];
    #pragma unroll
    for (int i = 0; i < 4; ++i)
        #pragma unroll
        for (int j = 0; j < 4; ++j) acc[i][j] = (f32x4){0.f, 0.f, 0.f, 0.f};

    const int arow = tid >> 1;
    const int ahalf = tid & 1;
    const int dcol = tid & 127;
    const int bhalf = tid >> 7;
    const size_t entcol = (size_t)(d0 + dcol);

    float ra[16], rb[16];

    auto loadA = [&](int k0) {
        int nbase = n0 + k0 + ahalf * 16;
        const float* asrc = aggf + (size_t)arow * N_ + nbase;
        #pragma unroll
        for (int c = 0; c < 2; ++c) {
            if (nbase + c * 8 + 7 < N_) {
                float4 g0 = *reinterpret_cast<const float4*>(asrc + c * 8);
                float4 g1 = *reinterpret_cast<const float4*>(asrc + c * 8 + 4);
                ra[c*8+0]=g0.x; ra[c*8+1]=g0.y; ra[c*8+2]=g0.z; ra[c*8+3]=g0.w;
                ra[c*8+4]=g1.x; ra[c*8+5]=g1.y; ra[c*8+6]=g1.z; ra[c*8+7]=g1.w;
            } else {
                #pragma unroll
                for (int j = 0; j < 8; ++j) {
                    int n = nbase + c * 8 + j;
                    ra[c*8+j] = (n < N_) ? aggf[(size_t)arow * N_ + n] : 0.f;
                }
            }
        }
    };
    auto loadB = [&](int k0) {
        int nb = n0 + k0 + bhalf * 16;
        #pragma unroll
        for (int j = 0; j < 16; ++j) {
            int n = nb + j;
            if (n > N_ - 1) n = N_ - 1;
            rb[j] = ent[(size_t)n * D_ + entcol];
        }
    };
    auto stage = [&](int bufbase) {
        #pragma unroll
        for (int c = 0; c < 2; ++c) {
            short8 hb, lb;
            #pragma unroll
            for (int j = 0; j < 8; ++j) {
                float f = ra[c*8+j];
                unsigned short h = rne_bf16(f);
                hb[j] = (short)h;
                lb[j] = (short)rne_bf16(f - bf16_to_f32(h));
            }
            *reinterpret_cast<short8*>(&lds[bufbase + OLDS_A_HI + arow * APITCH + ahalf * 16 + c * 8]) = hb;
            *reinterpret_cast<short8*>(&lds[bufbase + OLDS_A_LO + arow * APITCH + ahalf * 16 + c * 8]) = lb;
        }
        #pragma unroll
        for (int c = 0; c < 2; ++c) {
            short8 hb, lb;
            #pragma unroll
            for (int j = 0; j < 8; ++j) {
                float f = rb[c*8+j];
                unsigned short h = rne_bf16(f);
                hb[j] = (short)h;
                lb[j] = (short)rne_bf16(f - bf16_to_f32(h));
            }
            *reinterpret_cast<short8*>(&lds[bufbase + OLDS_B_HI + dcol * APITCH + bhalf * 16 + c * 8]) = hb;
            *reinterpret_cast<short8*>(&lds[bufbase + OLDS_B_LO + dcol * APITCH + bhalf * 16 + c * 8]) = lb;
        }
    };

    // prologue: stage tile 0, prefetch regs for tile 1
    loadA(0); loadB(0);
    stage(0);
    loadA(32); loadB(32);
    __syncthreads();

    for (int t = 0; t < 12; ++t) {
        const int base = (t & 1) * OG_BUF;
        const int nb2 = ((t + 1) & 1) * OG_BUF;
        if (t < 11) stage(nb2);                       // regs hold tile t+1
        if (t < 10) { loadA((t + 2) * 32); loadB((t + 2) * 32); }
        short8 ah[4], al[4], bh[4], bl[4];
        #pragma unroll
        for (int mi = 0; mi < 4; ++mi) {
            int r = m0w + mi * 16 + lm;
            ah[mi] = *reinterpret_cast<const short8*>(&lds[base + OLDS_A_HI + r * APITCH + kg * 8]);
            al[mi] = *reinterpret_cast<const short8*>(&lds[base + OLDS_A_LO + r * APITCH + kg * 8]);
        }
        #pragma unroll
        for (int nj = 0; nj < 4; ++nj) {
            int r = c0w + nj * 16 + lm;
            bh[nj] = *reinterpret_cast<const short8*>(&lds[base + OLDS_B_HI + r * APITCH + kg * 8]);
            bl[nj] = *reinterpret_cast<const short8*>(&lds[base + OLDS_B_LO + r * APITCH + kg * 8]);
        }
        #pragma unroll
        for (int mi = 0; mi < 4; ++mi)
            #pragma unroll
            for (int nj = 0; nj < 4; ++nj) {
                acc[mi][nj] = __builtin_amdgcn_mfma_f32_16x16x32_bf16(ah[mi], bh[nj], acc[mi][nj], 0, 0, 0);
                acc[mi][nj] = __builtin_amdgcn_mfma_f32_16x16x32_bf16(ah[mi], bl[nj], acc[mi][nj], 0, 0, 0);
                acc[mi][nj] = __builtin_amdgcn_mfma_f32_16x16x32_bf16(al[mi], bh[nj], acc[mi][nj], 0, 0, 0);
            }
        __syncthreads();
    }

    float* pbase = part + (size_t)chunk * 65536;
    #pragma unroll
    for (int nj = 0; nj < 4; ++nj) {
        int dcolo = d0 + c0w + nj * 16 + lm;
        #pragma unroll
        for (int mi = 0; mi < 4; ++mi) {
            int brow = m0w + mi * 16 + kg * 4;
            #pragma unroll
            for (int j = 0; j < 4; ++j)
                pbase[(size_t)(brow + j) * 512 + dcolo] = acc[mi][nj][j];
        }
    }
}

// ---------------- reduce partials + normalize by agg_sum ----------------
__global__ __launch_bounds__(256) void k_redout(const float* __restrict__ part,
                                                const float* __restrict__ stats,
                                                float* __restrict__ out) {
    int i = blockIdx.x * 256 + threadIdx.x;  // 0..65535
    int b = i >> 9;
    float s = 0.f;
    for (int c = 0; c < OCHUNK; ++c) s += part[(size_t)c * 65536 + i];
    out[i] = s / fmaxf(CLIPV, stats[ST_AGGSUM + b]);
}

extern "C" void kernel_launch(void* const* d_in, const int* in_sizes, int n_in,
                              void* d_out, int out_size, void* d_ws, size_t ws_size,
                              hipStream_t stream) {
    const float* ent = (const float*)d_in[0];
    const float* hv  = (const float*)d_in[1];
    const float* he  = (const float*)d_in[2];
    const float* pe  = (const float*)d_in[3];
    const float* ev  = (const float*)d_in[4];
    const int*   es  = (const int*)d_in[5];
    const int*   ed  = (const int*)d_in[6];
    float* out = (float*)d_out;
    float* ws = (float*)d_ws;

    unsigned short* tail_hi = (unsigned short*)(ws + OFF_TAIL);
    unsigned short* tail_lo = tail_hi + (size_t)AB_ * D_;

    hipMemsetAsync(ws + OFF_SYM, 0, (size_t)AB_ * N_ * sizeof(float), stream);
    hipMemsetAsync(ws + OFF_STATS, 0, 2048 * sizeof(float), stream);

    k_tail<<<512, 256, 0, stream>>>(he, pe, tail_hi, tail_lo);
    k_scatter<<<AB_, 256, 0, stream>>>(hv, ev, es, ed, ws + OFF_SYM);
    k_score<<<782, 256, 0, stream>>>(ent, tail_hi, tail_lo, ws + OFF_SCORE, ws + OFF_STATS);
    k_symsum<<<AB_ * 4, 256, 0, stream>>>(ws + OFF_SYM, ws + OFF_STATS);
    k_enhagg<<<B_ * 4, 256, 0, stream>>>(ws + OFF_SCORE, ws + OFF_SYM, ws + OFF_STATS);
    k_outgemm<<<OCHUNK * 4, 256, 0, stream>>>(ent, ws + OFF_SCORE, ws + OFF_SYM);
    k_redout<<<256, 256, 0, stream>>>(ws + OFF_SYM, ws + OFF_STATS, out);
}

// Round 9
// 324.399 us; speedup vs baseline: 1.1579x; 1.1066x over previous
//
#include <hip/hip_runtime.h>
#include <hip/hip_bf16.h>
#include <cstdint>
#include <cstddef>

// Problem constants
#define A_ 2
#define B_ 128
#define N_ 50000
#define D_ 512
#define E_ 4096
#define AB_ 256
#define CLIPV 1e-14f

// Workspace layout (float offsets)
static const size_t OFF_SYM   = 0;          // [AB_][N_] f32 symbolic; dead after k_enhagg -> outgemm partials
static const size_t OFF_SCORE = 12800000;   // [AB_][N_] p=exp(score); rows 0..127 overwritten in-place with agg f32
static const size_t OFF_TAIL  = 25600000;   // tail hi/lo bf16 (2 x 131072 ushort)
static const size_t OFF_STATS = 25731072;   // stats block (2048 floats)
// stats sub-offsets
#define ST_SYMSUM 0
#define ST_EXPSUM 512
#define ST_AGGSUM 1024
// out-gemm split-K geometry
#define CH_K 384
#define OCHUNK 131   // ceil(50000/384)

typedef __attribute__((ext_vector_type(8))) short short8;
typedef __attribute__((ext_vector_type(4))) float f32x4;

// split f32 -> bf16 hi/lo via hardware cvt (rounding mode of hi irrelevant: lo compensates)
__device__ __forceinline__ void split_bf16(float f, unsigned short& h, unsigned short& lo) {
    __hip_bfloat16 bh = __float2bfloat16(f);
    float hf = __bfloat162float(bh);
    __hip_bfloat16 bl = __float2bfloat16(f - hf);
    h = *reinterpret_cast<unsigned short*>(&bh);
    lo = *reinterpret_cast<unsigned short*>(&bl);
}
__device__ __forceinline__ void cvt8_cheap(const float4& a, const float4& b, short8& hb, short8& lb) {
    float f[8] = {a.x, a.y, a.z, a.w, b.x, b.y, b.z, b.w};
    #pragma unroll
    for (int j = 0; j < 8; ++j) {
        unsigned short h, l;
        split_bf16(f[j], h, l);
        hb[j] = (short)h;
        lb[j] = (short)l;
    }
}

// ---------------- tail = head + pred, split to bf16 hi/lo ----------------
__global__ __launch_bounds__(256) void k_tail(const float* __restrict__ head,
                                              const float* __restrict__ pred,
                                              unsigned short* __restrict__ tail_hi,
                                              unsigned short* __restrict__ tail_lo) {
    int i = blockIdx.x * 256 + threadIdx.x;
    if (i < AB_ * D_) {
        float t = head[i] + pred[i];
        unsigned short h, l;
        split_bf16(t, h, l);
        tail_hi[i] = h;
        tail_lo[i] = l;
    }
}

// ---------------- scatter-add symbolic ----------------
__global__ __launch_bounds__(256) void k_scatter(const float* __restrict__ hv,
                                                 const float* __restrict__ ev,
                                                 const int* __restrict__ es,
                                                 const int* __restrict__ ed,
                                                 float* __restrict__ sym) {
    int ab = blockIdx.x;
    const float* hvr = hv + (size_t)ab * N_;
    float* symr = sym + (size_t)ab * N_;
    int base = ab * E_;
    for (int e = threadIdx.x; e < E_; e += 256) {
        float v = ev[base + e];
        int s = es[base + e];
        int d = ed[base + e];
        atomicAdd(&symr[d], v * hvr[s]);
    }
}

// ---------------- masked sym row-sums ----------------
__global__ __launch_bounds__(256) void k_symsum(const float* __restrict__ sym,
                                                float* __restrict__ stats) {
    int ab = blockIdx.x >> 2, part = blockIdx.x & 3;
    const float4* src = reinterpret_cast<const float4*>(sym + (size_t)ab * N_ + part * 12500);
    float s = 0.f;
    for (int i = threadIdx.x; i < 3125; i += 256) {
        float4 v = src[i];
        s += ((v.x < CLIPV) ? 0.f : v.x) + ((v.y < CLIPV) ? 0.f : v.y)
           + ((v.z < CLIPV) ? 0.f : v.z) + ((v.w < CLIPV) ? 0.f : v.w);
    }
    __shared__ float red[256];
    red[threadIdx.x] = s;
    __syncthreads();
    for (int st = 128; st > 0; st >>= 1) {
        if (threadIdx.x < st) red[threadIdx.x] += red[threadIdx.x + st];
        __syncthreads();
    }
    if (threadIdx.x == 0) atomicAdd(&stats[ST_SYMSUM + ab], red[0]);
}

// ---------------- score GEMM: R3 structure + hidden loads + cheap converts, fused exp ----------------
// Block: 256 m x 64 n, 4 waves (wave tile 64x64), BK=32, single 50 KB buffer (3 blocks/CU).
// Per K-step: write LDS from regs(t) -> barrier -> issue global loads(t+1) -> MFMA(t) -> barrier.
#define S3PITCH 40
#define S3A_HI 0
#define S3A_LO 10240
#define S3B_HI 20480
#define S3B_LO 23040

__global__ __launch_bounds__(256) void k_score(const float* __restrict__ ent,
                                               const unsigned short* __restrict__ tail_hi,
                                               const unsigned short* __restrict__ tail_lo,
                                               float* __restrict__ p_out,
                                               float* __restrict__ stats) {
    __shared__ unsigned short lds[25600];   // 50 KB
    const int tid = threadIdx.x;
    const int w = tid >> 6;
    const int l = tid & 63;
    const int lm = l & 15;
    const int kg = l >> 4;
    const int n0 = blockIdx.x * 64;
    const int m0w = w * 64;

    f32x4 acc[4][4];
    #pragma unroll
    for (int i = 0; i < 4; ++i)
        #pragma unroll
        for (int j = 0; j < 4; ++j) acc[i][j] = (f32x4){0.f, 0.f, 0.f, 0.f};

    // A staging role: thread t owns tail row t (32 ushorts of hi + lo per step)
    const unsigned short* gAh = tail_hi + (size_t)tid * D_;
    const unsigned short* gAl = tail_lo + (size_t)tid * D_;
    // B staging role: n-row bn = tid>>2, 8-float chunk bc = tid&3
    const int bn = tid >> 2;
    const int bc = tid & 3;
    int entrow = n0 + bn;
    if (entrow > N_ - 1) entrow = N_ - 1;
    const float* entp = ent + (size_t)entrow * D_ + bc * 8;

    // staging registers (carry tile t across the MFMA phase of t-1)
    short8 rAh[4], rAl[4];
    float4 rB0, rB1;

    // prologue: load tile 0 into regs
    #pragma unroll
    for (int c = 0; c < 4; ++c) {
        rAh[c] = *reinterpret_cast<const short8*>(gAh + c * 8);
        rAl[c] = *reinterpret_cast<const short8*>(gAl + c * 8);
    }
    rB0 = *reinterpret_cast<const float4*>(entp);
    rB1 = *reinterpret_cast<const float4*>(entp + 4);

    for (int t = 0; t < 16; ++t) {
        // phase 1: write tile t from regs to LDS (A passthrough, B converted)
        #pragma unroll
        for (int c = 0; c < 4; ++c) {
            *reinterpret_cast<short8*>(&lds[S3A_HI + tid * S3PITCH + c * 8]) = rAh[c];
            *reinterpret_cast<short8*>(&lds[S3A_LO + tid * S3PITCH + c * 8]) = rAl[c];
        }
        {
            short8 hb, lb;
            cvt8_cheap(rB0, rB1, hb, lb);
            *reinterpret_cast<short8*>(&lds[S3B_HI + bn * S3PITCH + bc * 8]) = hb;
            *reinterpret_cast<short8*>(&lds[S3B_LO + bn * S3PITCH + bc * 8]) = lb;
        }
        __syncthreads();
        // phase 2: issue tile t+1 global loads (fly under the MFMA phase)
        if (t < 15) {
            const int k1 = (t + 1) * 32;
            #pragma unroll
            for (int c = 0; c < 4; ++c) {
                rAh[c] = *reinterpret_cast<const short8*>(gAh + k1 + c * 8);
                rAl[c] = *reinterpret_cast<const short8*>(gAl + k1 + c * 8);
            }
            rB0 = *reinterpret_cast<const float4*>(entp + k1);
            rB1 = *reinterpret_cast<const float4*>(entp + k1 + 4);
        }
        // phase 3: fragments + MFMA on tile t
        short8 bh[4], bl[4];
        #pragma unroll
        for (int nj = 0; nj < 4; ++nj) {
            int br = nj * 16 + lm;
            bh[nj] = *reinterpret_cast<const short8*>(&lds[S3B_HI + br * S3PITCH + kg * 8]);
            bl[nj] = *reinterpret_cast<const short8*>(&lds[S3B_LO + br * S3PITCH + kg * 8]);
        }
        #pragma unroll
        for (int mi = 0; mi < 4; ++mi) {
            int ar = m0w + mi * 16 + lm;
            short8 ah = *reinterpret_cast<const short8*>(&lds[S3A_HI + ar * S3PITCH + kg * 8]);
            short8 al = *reinterpret_cast<const short8*>(&lds[S3A_LO + ar * S3PITCH + kg * 8]);
            #pragma unroll
            for (int nj = 0; nj < 4; ++nj) {
                acc[mi][nj] = __builtin_amdgcn_mfma_f32_16x16x32_bf16(ah, bh[nj], acc[mi][nj], 0, 0, 0);
                acc[mi][nj] = __builtin_amdgcn_mfma_f32_16x16x32_bf16(ah, bl[nj], acc[mi][nj], 0, 0, 0);
                acc[mi][nj] = __builtin_amdgcn_mfma_f32_16x16x32_bf16(al, bh[nj], acc[mi][nj], 0, 0, 0);
            }
        }
        __syncthreads();
    }

    // epilogue: p = exp(score) (no max-sub; scores are small), store + per-row expsum
    #pragma unroll
    for (int mi = 0; mi < 4; ++mi) {
        #pragma unroll
        for (int j = 0; j < 4; ++j) {
            int row = m0w + mi * 16 + kg * 4 + j;
            float rsum = 0.f;
            #pragma unroll
            for (int nj = 0; nj < 4; ++nj) {
                int col = n0 + nj * 16 + lm;
                if (col < N_) {
                    float pv = expf(acc[mi][nj][j]);
                    p_out[(size_t)row * N_ + col] = pv;
                    rsum += pv;
                }
            }
            rsum += __shfl_xor(rsum, 1);
            rsum += __shfl_xor(rsum, 2);
            rsum += __shfl_xor(rsum, 4);
            rsum += __shfl_xor(rsum, 8);
            if (lm == 0) atomicAdd(&stats[ST_EXPSUM + row], rsum);
        }
    }
}

// ---------------- fused enhance + product + aggsum; agg f32 written IN PLACE over p rows 0..127 ----------------
__global__ __launch_bounds__(256) void k_enhagg(float* __restrict__ p,
                                                const float* __restrict__ sym,
                                                float* __restrict__ stats) {
    int b = blockIdx.x >> 2, part = blockIdx.x & 3;
    size_t off0 = (size_t)b * N_ + part * 12500;
    size_t off1 = (size_t)(128 + b) * N_ + part * 12500;
    float is0 = 1.f / fmaxf(CLIPV, stats[ST_SYMSUM + b]);
    float is1 = 1.f / fmaxf(CLIPV, stats[ST_SYMSUM + 128 + b]);
    float ie0 = 1.f / fmaxf(CLIPV, stats[ST_EXPSUM + b]);
    float ie1 = 1.f / fmaxf(CLIPV, stats[ST_EXPSUM + 128 + b]);
    const float4* s0p = reinterpret_cast<const float4*>(sym + off0);
    const float4* s1p = reinterpret_cast<const float4*>(sym + off1);
    float4* p0p = reinterpret_cast<float4*>(p + off0);
    const float4* p1p = reinterpret_cast<const float4*>(p + off1);
    float local = 0.f;
    for (int i = threadIdx.x; i < 3125; i += 256) {
        float4 s0 = s0p[i], s1 = s1p[i], q0 = p0p[i], q1 = p1p[i];
        float sv0[4] = {s0.x, s0.y, s0.z, s0.w};
        float sv1[4] = {s1.x, s1.y, s1.z, s1.w};
        float qv0[4] = {q0.x, q0.y, q0.z, q0.w};
        float qv1[4] = {q1.x, q1.y, q1.z, q1.w};
        float vv[4];
        #pragma unroll
        for (int c = 0; c < 4; ++c) {
            float a0 = (sv0[c] < CLIPV) ? 0.f : sv0[c];
            float a1 = (sv1[c] < CLIPV) ? 0.f : sv1[c];
            float e0 = a0 * is0 + qv0[c] * ie0; e0 = (e0 < CLIPV) ? 0.f : e0;
            float e1 = a1 * is1 + qv1[c] * ie1; e1 = (e1 < CLIPV) ? 0.f : e1;
            float v = e0 * e1 * 0.25f;
            v = (v < CLIPV) ? 0.f : v;
            local += v;
            vv[c] = v;
        }
        float4 o; o.x = vv[0]; o.y = vv[1]; o.z = vv[2]; o.w = vv[3];
        p0p[i] = o;
    }
    __shared__ float red[256];
    red[threadIdx.x] = local;
    __syncthreads();
    for (int st = 128; st > 0; st >>= 1) {
        if (threadIdx.x < st) red[threadIdx.x] += red[threadIdx.x + st];
        __syncthreads();
    }
    if (threadIdx.x == 0) atomicAdd(&stats[ST_AGGSUM + b], red[0]);
}

// ---------------- out GEMM via split-bf16 MFMA, split-K, double-buffered, 1 barrier/K-step ----------------
#define APITCH 40
#define OG_BUF 20480
#define OLDS_A_HI 0
#define OLDS_A_LO 5120
#define OLDS_B_HI 10240
#define OLDS_B_LO 15360

__global__ __launch_bounds__(256) void k_outgemm(const float* __restrict__ ent,
                                                 const float* __restrict__ aggf,
                                                 float* __restrict__ part) {
    __shared__ unsigned short lds[40960];   // 80 KB: 2 buffers
    const int bid = blockIdx.x;
    const int chunk = bid >> 2, dt = bid & 3;
    const int n0 = chunk * CH_K, d0 = dt * 128;
    const int tid = threadIdx.x;
    const int w = tid >> 6;
    const int l = tid & 63;
    const int lm = l & 15;
    const int kg = l >> 4;
    const int m0w = (w >> 1) * 64;
    const int c0w = (w & 1) * 64;

    f32x4 acc[4][4];
    #pragma unroll
    for (int i = 0; i < 4; ++i)
        #pragma unroll
        for (int j = 0; j < 4; ++j) acc[i][j] = (f32x4){0.f, 0.f, 0.f, 0.f};

    const int arow = tid >> 1;
    const int ahalf = tid & 1;
    const int dcol = tid & 127;
    const int bhalf = tid >> 7;
    const size_t entcol = (size_t)(d0 + dcol);

    float ra[16], rb[16];

    auto loadA = [&](int k0) {
        int nbase = n0 + k0 + ahalf * 16;
        const float* asrc = aggf + (size_t)arow * N_ + nbase;
        #pragma unroll
        for (int c = 0; c < 2; ++c) {
            if (nbase + c * 8 + 7 < N_) {
                float4 g0 = *reinterpret_cast<const float4*>(asrc + c * 8);
                float4 g1 = *reinterpret_cast<const float4*>(asrc + c * 8 + 4);
                ra[c*8+0]=g0.x; ra[c*8+1]=g0.y; ra[c*8+2]=g0.z; ra[c*8+3]=g0.w;
                ra[c*8+4]=g1.x; ra[c*8+5]=g1.y; ra[c*8+6]=g1.z; ra[c*8+7]=g1.w;
            } else {
                #pragma unroll
                for (int j = 0; j < 8; ++j) {
                    int n = nbase + c * 8 + j;
                    ra[c*8+j] = (n < N_) ? aggf[(size_t)arow * N_ + n] : 0.f;
                }
            }
        }
    };
    auto loadB = [&](int k0) {
        int nb = n0 + k0 + bhalf * 16;
        #pragma unroll
        for (int j = 0; j < 16; ++j) {
            int n = nb + j;
            if (n > N_ - 1) n = N_ - 1;
            rb[j] = ent[(size_t)n * D_ + entcol];
        }
    };
    auto stage = [&](int bufbase) {
        #pragma unroll
        for (int c = 0; c < 2; ++c) {
            short8 hb, lb;
            #pragma unroll
            for (int j = 0; j < 8; ++j) {
                unsigned short h, lo;
                split_bf16(ra[c*8+j], h, lo);
                hb[j] = (short)h;
                lb[j] = (short)lo;
            }
            *reinterpret_cast<short8*>(&lds[bufbase + OLDS_A_HI + arow * APITCH + ahalf * 16 + c * 8]) = hb;
            *reinterpret_cast<short8*>(&lds[bufbase + OLDS_A_LO + arow * APITCH + ahalf * 16 + c * 8]) = lb;
        }
        #pragma unroll
        for (int c = 0; c < 2; ++c) {
            short8 hb, lb;
            #pragma unroll
            for (int j = 0; j < 8; ++j) {
                unsigned short h, lo;
                split_bf16(rb[c*8+j], h, lo);
                hb[j] = (short)h;
                lb[j] = (short)lo;
            }
            *reinterpret_cast<short8*>(&lds[bufbase + OLDS_B_HI + dcol * APITCH + bhalf * 16 + c * 8]) = hb;
            *reinterpret_cast<short8*>(&lds[bufbase + OLDS_B_LO + dcol * APITCH + bhalf * 16 + c * 8]) = lb;
        }
    };

    // prologue: stage tile 0, prefetch regs for tile 1
    loadA(0); loadB(0);
    stage(0);
    loadA(32); loadB(32);
    __syncthreads();

    for (int t = 0; t < 12; ++t) {
        const int base = (t & 1) * OG_BUF;
        const int nb2 = ((t + 1) & 1) * OG_BUF;
        if (t < 11) stage(nb2);                       // regs hold tile t+1
        if (t < 10) { loadA((t + 2) * 32); loadB((t + 2) * 32); }
        short8 ah[4], al[4], bh[4], bl[4];
        #pragma unroll
        for (int mi = 0; mi < 4; ++mi) {
            int r = m0w + mi * 16 + lm;
            ah[mi] = *reinterpret_cast<const short8*>(&lds[base + OLDS_A_HI + r * APITCH + kg * 8]);
            al[mi] = *reinterpret_cast<const short8*>(&lds[base + OLDS_A_LO + r * APITCH + kg * 8]);
        }
        #pragma unroll
        for (int nj = 0; nj < 4; ++nj) {
            int r = c0w + nj * 16 + lm;
            bh[nj] = *reinterpret_cast<const short8*>(&lds[base + OLDS_B_HI + r * APITCH + kg * 8]);
            bl[nj] = *reinterpret_cast<const short8*>(&lds[base + OLDS_B_LO + r * APITCH + kg * 8]);
        }
        #pragma unroll
        for (int mi = 0; mi < 4; ++mi)
            #pragma unroll
            for (int nj = 0; nj < 4; ++nj) {
                acc[mi][nj] = __builtin_amdgcn_mfma_f32_16x16x32_bf16(ah[mi], bh[nj], acc[mi][nj], 0, 0, 0);
                acc[mi][nj] = __builtin_amdgcn_mfma_f32_16x16x32_bf16(ah[mi], bl[nj], acc[mi][nj], 0, 0, 0);
                acc[mi][nj] = __builtin_amdgcn_mfma_f32_16x16x32_bf16(al[mi], bh[nj], acc[mi][nj], 0, 0, 0);
            }
        __syncthreads();
    }

    float* pbase = part + (size_t)chunk * 65536;
    #pragma unroll
    for (int nj = 0; nj < 4; ++nj) {
        int dcolo = d0 + c0w + nj * 16 + lm;
        #pragma unroll
        for (int mi = 0; mi < 4; ++mi) {
            int brow = m0w + mi * 16 + kg * 4;
            #pragma unroll
            for (int j = 0; j < 4; ++j)
                pbase[(size_t)(brow + j) * 512 + dcolo] = acc[mi][nj][j];
        }
    }
}

// ---------------- reduce partials + normalize by agg_sum ----------------
__global__ __launch_bounds__(256) void k_redout(const float* __restrict__ part,
                                                const float* __restrict__ stats,
                                                float* __restrict__ out) {
    int i = blockIdx.x * 256 + threadIdx.x;  // 0..65535
    int b = i >> 9;
    float s = 0.f;
    for (int c = 0; c < OCHUNK; ++c) s += part[(size_t)c * 65536 + i];
    out[i] = s / fmaxf(CLIPV, stats[ST_AGGSUM + b]);
}

extern "C" void kernel_launch(void* const* d_in, const int* in_sizes, int n_in,
                              void* d_out, int out_size, void* d_ws, size_t ws_size,
                              hipStream_t stream) {
    const float* ent = (const float*)d_in[0];
    const float* hv  = (const float*)d_in[1];
    const float* he  = (const float*)d_in[2];
    const float* pe  = (const float*)d_in[3];
    const float* ev  = (const float*)d_in[4];
    const int*   es  = (const int*)d_in[5];
    const int*   ed  = (const int*)d_in[6];
    float* out = (float*)d_out;
    float* ws = (float*)d_ws;

    unsigned short* tail_hi = (unsigned short*)(ws + OFF_TAIL);
    unsigned short* tail_lo = tail_hi + (size_t)AB_ * D_;

    hipMemsetAsync(ws + OFF_SYM, 0, (size_t)AB_ * N_ * sizeof(float), stream);
    hipMemsetAsync(ws + OFF_STATS, 0, 2048 * sizeof(float), stream);

    k_tail<<<512, 256, 0, stream>>>(he, pe, tail_hi, tail_lo);
    k_scatter<<<AB_, 256, 0, stream>>>(hv, ev, es, ed, ws + OFF_SYM);
    k_score<<<782, 256, 0, stream>>>(ent, tail_hi, tail_lo, ws + OFF_SCORE, ws + OFF_STATS);
    k_symsum<<<AB_ * 4, 256, 0, stream>>>(ws + OFF_SYM, ws + OFF_STATS);
    k_enhagg<<<B_ * 4, 256, 0, stream>>>(ws + OFF_SCORE, ws + OFF_SYM, ws + OFF_STATS);
    k_outgemm<<<OCHUNK * 4, 256, 0, stream>>>(ent, ws + OFF_SCORE, ws + OFF_SYM);
    k_redout<<<256, 256, 0, stream>>>(ws + OFF_SYM, ws + OFF_STATS, out);
}

// Round 10
// 293.865 us; speedup vs baseline: 1.2782x; 1.1039x over previous
//
#include <hip/hip_runtime.h>
#include <hip/hip_bf16.h>
#include <cstdint>
#include <cstddef>

// Problem constants
#define A_ 2
#define B_ 128
#define N_ 50000
#define D_ 512
#define E_ 4096
#define AB_ 256
#define CLIPV 1e-14f

// Workspace layout (float offsets)
static const size_t OFF_SYM   = 0;          // [AB_][N_] f32 symbolic; dead after k_enhagg -> outgemm partials
static const size_t OFF_SCORE = 12800000;   // [AB_][N_] p=exp(score); rows 0..127 overwritten in-place with agg f32
static const size_t OFF_TAIL  = 25600000;   // tail hi/lo bf16 (2 x 131072 ushort)
static const size_t OFF_STATS = 25731072;   // stats block (2048 floats)
// stats sub-offsets
#define ST_SYMSUM 0
#define ST_EXPSUM 512
#define ST_AGGSUM 1024
// out-gemm split-K geometry
#define CH_K 384
#define OCHUNK 131   // ceil(50000/384)

typedef __attribute__((ext_vector_type(8))) short short8;
typedef __attribute__((ext_vector_type(4))) float f32x4;

// split f32 -> bf16 hi/lo via hardware cvt (rounding mode of hi irrelevant: lo compensates)
__device__ __forceinline__ void split_bf16(float f, unsigned short& h, unsigned short& lo) {
    __hip_bfloat16 bh = __float2bfloat16(f);
    float hf = __bfloat162float(bh);
    __hip_bfloat16 bl = __float2bfloat16(f - hf);
    h = *reinterpret_cast<unsigned short*>(&bh);
    lo = *reinterpret_cast<unsigned short*>(&bl);
}
__device__ __forceinline__ unsigned short to_bf16(float f) {
    __hip_bfloat16 bh = __float2bfloat16(f);
    return *reinterpret_cast<unsigned short*>(&bh);
}
__device__ __forceinline__ void gld_lds16(const unsigned short* g, unsigned short* l) {
    __builtin_amdgcn_global_load_lds(
        (const __attribute__((address_space(1))) void*)g,
        (__attribute__((address_space(3))) void*)l, 16, 0, 0);
}

// ---------------- tail = head + pred -> bf16 ----------------
__global__ __launch_bounds__(256) void k_tail(const float* __restrict__ head,
                                              const float* __restrict__ pred,
                                              unsigned short* __restrict__ tail_hi) {
    int i = blockIdx.x * 256 + threadIdx.x;
    if (i < AB_ * D_) {
        float t = head[i] + pred[i];
        tail_hi[i] = to_bf16(t);
    }
}

// ---------------- scatter-add symbolic ----------------
__global__ __launch_bounds__(256) void k_scatter(const float* __restrict__ hv,
                                                 const float* __restrict__ ev,
                                                 const int* __restrict__ es,
                                                 const int* __restrict__ ed,
                                                 float* __restrict__ sym) {
    int ab = blockIdx.x;
    const float* hvr = hv + (size_t)ab * N_;
    float* symr = sym + (size_t)ab * N_;
    int base = ab * E_;
    for (int e = threadIdx.x; e < E_; e += 256) {
        float v = ev[base + e];
        int s = es[base + e];
        int d = ed[base + e];
        atomicAdd(&symr[d], v * hvr[s]);
    }
}

// ---------------- masked sym row-sums ----------------
__global__ __launch_bounds__(256) void k_symsum(const float* __restrict__ sym,
                                                float* __restrict__ stats) {
    int ab = blockIdx.x >> 2, part = blockIdx.x & 3;
    const float4* src = reinterpret_cast<const float4*>(sym + (size_t)ab * N_ + part * 12500);
    float s = 0.f;
    for (int i = threadIdx.x; i < 3125; i += 256) {
        float4 v = src[i];
        s += ((v.x < CLIPV) ? 0.f : v.x) + ((v.y < CLIPV) ? 0.f : v.y)
           + ((v.z < CLIPV) ? 0.f : v.z) + ((v.w < CLIPV) ? 0.f : v.w);
    }
    __shared__ float red[256];
    red[threadIdx.x] = s;
    __syncthreads();
    for (int st = 128; st > 0; st >>= 1) {
        if (threadIdx.x < st) red[threadIdx.x] += red[threadIdx.x + st];
        __syncthreads();
    }
    if (threadIdx.x == 0) atomicAdd(&stats[ST_SYMSUM + ab], red[0]);
}

// ---------------- score GEMM: plain bf16 MFMA (no hi/lo), dbuf 1-barrier, fused exp ----------------
// Block: 256 m x 64 n, 4 waves (wave tile 64x64), BK=32, 2 buffers of 21 KB (42 KB -> 3 blocks/CU).
// A (tail bf16) via global_load_lds (linear [256][32]); B (ent f32) reg-prefetch + cvt-hi store.
// 16 MFMA/wave/step (was 48).
#define SC_BUF 10752      // ushorts per buffer: A 8192 + B 2560
#define SCB_OFF 8192
#define SBPITCH 40

__global__ __launch_bounds__(256) void k_score(const float* __restrict__ ent,
                                               const unsigned short* __restrict__ tail_hi,
                                               float* __restrict__ p_out,
                                               float* __restrict__ stats) {
    __shared__ unsigned short lds[21504];
    const int tid = threadIdx.x;
    const int w = tid >> 6;
    const int l = tid & 63;
    const int lm = l & 15;
    const int kg = l >> 4;
    const int n0 = blockIdx.x * 64;
    const int m0w = w * 64;

    f32x4 acc[4][4];
    #pragma unroll
    for (int i = 0; i < 4; ++i)
        #pragma unroll
        for (int j = 0; j < 4; ++j) acc[i][j] = (f32x4){0.f, 0.f, 0.f, 0.f};

    // A gld role: wave w, lane l covers row w*16 + i*64 + (l>>2), k-chunk (l&3)*8
    const int arow_base = w * 16 + (l >> 2);
    const int ak = (l & 3) * 8;
    // B staging role: n-row bn = tid>>2, chunk bc = tid&3
    const int bn = tid >> 2;
    const int bc = tid & 3;
    int entrow = n0 + bn;
    if (entrow > N_ - 1) entrow = N_ - 1;
    const float* entp = ent + (size_t)entrow * D_ + bc * 8;

    float4 rB0, rB1;

    // prologue: stage tile 0 into buf0
    #pragma unroll
    for (int i = 0; i < 4; ++i) {
        int row = arow_base + i * 64;
        gld_lds16(tail_hi + (size_t)row * D_ + ak, &lds[w * 512 + i * 2048]);
    }
    {
        float4 b0 = *reinterpret_cast<const float4*>(entp);
        float4 b1 = *reinterpret_cast<const float4*>(entp + 4);
        short8 hb;
        hb[0]=(short)to_bf16(b0.x); hb[1]=(short)to_bf16(b0.y); hb[2]=(short)to_bf16(b0.z); hb[3]=(short)to_bf16(b0.w);
        hb[4]=(short)to_bf16(b1.x); hb[5]=(short)to_bf16(b1.y); hb[6]=(short)to_bf16(b1.z); hb[7]=(short)to_bf16(b1.w);
        *reinterpret_cast<short8*>(&lds[SCB_OFF + bn * SBPITCH + bc * 8]) = hb;
    }
    // prefetch B regs for tile 1
    rB0 = *reinterpret_cast<const float4*>(entp + 32);
    rB1 = *reinterpret_cast<const float4*>(entp + 36);
    __syncthreads();

    for (int t = 0; t < 16; ++t) {
        const int base = (t & 1) * SC_BUF;
        const int nb2 = ((t + 1) & 1) * SC_BUF;
        if (t < 15) {
            const int k1 = (t + 1) * 32;
            #pragma unroll
            for (int i = 0; i < 4; ++i) {
                int row = arow_base + i * 64;
                gld_lds16(tail_hi + (size_t)row * D_ + k1 + ak, &lds[nb2 + w * 512 + i * 2048]);
            }
            short8 hb;
            hb[0]=(short)to_bf16(rB0.x); hb[1]=(short)to_bf16(rB0.y); hb[2]=(short)to_bf16(rB0.z); hb[3]=(short)to_bf16(rB0.w);
            hb[4]=(short)to_bf16(rB1.x); hb[5]=(short)to_bf16(rB1.y); hb[6]=(short)to_bf16(rB1.z); hb[7]=(short)to_bf16(rB1.w);
            *reinterpret_cast<short8*>(&lds[nb2 + SCB_OFF + bn * SBPITCH + bc * 8]) = hb;
        }
        if (t < 14) {
            const int k2 = (t + 2) * 32;
            rB0 = *reinterpret_cast<const float4*>(entp + k2);
            rB1 = *reinterpret_cast<const float4*>(entp + k2 + 4);
        }
        // fragments + 16 MFMA on tile t
        short8 bh[4];
        #pragma unroll
        for (int nj = 0; nj < 4; ++nj) {
            int br = nj * 16 + lm;
            bh[nj] = *reinterpret_cast<const short8*>(&lds[base + SCB_OFF + br * SBPITCH + kg * 8]);
        }
        #pragma unroll
        for (int mi = 0; mi < 4; ++mi) {
            int ar = m0w + mi * 16 + lm;
            short8 ah = *reinterpret_cast<const short8*>(&lds[base + ar * 32 + kg * 8]);
            #pragma unroll
            for (int nj = 0; nj < 4; ++nj)
                acc[mi][nj] = __builtin_amdgcn_mfma_f32_16x16x32_bf16(ah, bh[nj], acc[mi][nj], 0, 0, 0);
        }
        __syncthreads();
    }

    // epilogue: p = exp(score) (no max-sub; scores are small), store + per-row expsum
    #pragma unroll
    for (int mi = 0; mi < 4; ++mi) {
        #pragma unroll
        for (int j = 0; j < 4; ++j) {
            int row = m0w + mi * 16 + kg * 4 + j;
            float rsum = 0.f;
            #pragma unroll
            for (int nj = 0; nj < 4; ++nj) {
                int col = n0 + nj * 16 + lm;
                if (col < N_) {
                    float pv = expf(acc[mi][nj][j]);
                    p_out[(size_t)row * N_ + col] = pv;
                    rsum += pv;
                }
            }
            rsum += __shfl_xor(rsum, 1);
            rsum += __shfl_xor(rsum, 2);
            rsum += __shfl_xor(rsum, 4);
            rsum += __shfl_xor(rsum, 8);
            if (lm == 0) atomicAdd(&stats[ST_EXPSUM + row], rsum);
        }
    }
}

// ---------------- fused enhance + product + aggsum; agg f32 written IN PLACE over p rows 0..127 ----------------
__global__ __launch_bounds__(256) void k_enhagg(float* __restrict__ p,
                                                const float* __restrict__ sym,
                                                float* __restrict__ stats) {
    int b = blockIdx.x >> 2, part = blockIdx.x & 3;
    size_t off0 = (size_t)b * N_ + part * 12500;
    size_t off1 = (size_t)(128 + b) * N_ + part * 12500;
    float is0 = 1.f / fmaxf(CLIPV, stats[ST_SYMSUM + b]);
    float is1 = 1.f / fmaxf(CLIPV, stats[ST_SYMSUM + 128 + b]);
    float ie0 = 1.f / fmaxf(CLIPV, stats[ST_EXPSUM + b]);
    float ie1 = 1.f / fmaxf(CLIPV, stats[ST_EXPSUM + 128 + b]);
    const float4* s0p = reinterpret_cast<const float4*>(sym + off0);
    const float4* s1p = reinterpret_cast<const float4*>(sym + off1);
    float4* p0p = reinterpret_cast<float4*>(p + off0);
    const float4* p1p = reinterpret_cast<const float4*>(p + off1);
    float local = 0.f;
    for (int i = threadIdx.x; i < 3125; i += 256) {
        float4 s0 = s0p[i], s1 = s1p[i], q0 = p0p[i], q1 = p1p[i];
        float sv0[4] = {s0.x, s0.y, s0.z, s0.w};
        float sv1[4] = {s1.x, s1.y, s1.z, s1.w};
        float qv0[4] = {q0.x, q0.y, q0.z, q0.w};
        float qv1[4] = {q1.x, q1.y, q1.z, q1.w};
        float vv[4];
        #pragma unroll
        for (int c = 0; c < 4; ++c) {
            float a0 = (sv0[c] < CLIPV) ? 0.f : sv0[c];
            float a1 = (sv1[c] < CLIPV) ? 0.f : sv1[c];
            float e0 = a0 * is0 + qv0[c] * ie0; e0 = (e0 < CLIPV) ? 0.f : e0;
            float e1 = a1 * is1 + qv1[c] * ie1; e1 = (e1 < CLIPV) ? 0.f : e1;
            float v = e0 * e1 * 0.25f;
            v = (v < CLIPV) ? 0.f : v;
            local += v;
            vv[c] = v;
        }
        float4 o; o.x = vv[0]; o.y = vv[1]; o.z = vv[2]; o.w = vv[3];
        p0p[i] = o;
    }
    __shared__ float red[256];
    red[threadIdx.x] = local;
    __syncthreads();
    for (int st = 128; st > 0; st >>= 1) {
        if (threadIdx.x < st) red[threadIdx.x] += red[threadIdx.x + st];
        __syncthreads();
    }
    if (threadIdx.x == 0) atomicAdd(&stats[ST_AGGSUM + b], red[0]);
}

// ---------------- out GEMM via split-bf16 MFMA, split-K, double-buffered, 1 barrier/K-step ----------------
#define APITCH 40
#define OG_BUF 20480
#define OLDS_A_HI 0
#define OLDS_A_LO 5120
#define OLDS_B_HI 10240
#define OLDS_B_LO 15360

__global__ __launch_bounds__(256) void k_outgemm(const float* __restrict__ ent,
                                                 const float* __restrict__ aggf,
                                                 float* __restrict__ part) {
    __shared__ unsigned short lds[40960];   // 80 KB: 2 buffers
    const int bid = blockIdx.x;
    const int chunk = bid >> 2, dt = bid & 3;
    const int n0 = chunk * CH_K, d0 = dt * 128;
    const int tid = threadIdx.x;
    const int w = tid >> 6;
    const int l = tid & 63;
    const int lm = l & 15;
    const int kg = l >> 4;
    const int m0w = (w >> 1) * 64;
    const int c0w = (w & 1) * 64;

    f32x4 acc[4][4];
    #pragma unroll
    for (int i = 0; i < 4; ++i)
        #pragma unroll
        for (int j = 0; j < 4; ++j) acc[i][j] = (f32x4){0.f, 0.f, 0.f, 0.f};

    const int arow = tid >> 1;
    const int ahalf = tid & 1;
    const int dcol = tid & 127;
    const int bhalf = tid >> 7;
    const size_t entcol = (size_t)(d0 + dcol);

    float ra[16], rb[16];

    auto loadA = [&](int k0) {
        int nbase = n0 + k0 + ahalf * 16;
        const float* asrc = aggf + (size_t)arow * N_ + nbase;
        #pragma unroll
        for (int c = 0; c < 2; ++c) {
            if (nbase + c * 8 + 7 < N_) {
                float4 g0 = *reinterpret_cast<const float4*>(asrc + c * 8);
                float4 g1 = *reinterpret_cast<const float4*>(asrc + c * 8 + 4);
                ra[c*8+0]=g0.x; ra[c*8+1]=g0.y; ra[c*8+2]=g0.z; ra[c*8+3]=g0.w;
                ra[c*8+4]=g1.x; ra[c*8+5]=g1.y; ra[c*8+6]=g1.z; ra[c*8+7]=g1.w;
            } else {
                #pragma unroll
                for (int j = 0; j < 8; ++j) {
                    int n = nbase + c * 8 + j;
                    ra[c*8+j] = (n < N_) ? aggf[(size_t)arow * N_ + n] : 0.f;
                }
            }
        }
    };
    auto loadB = [&](int k0) {
        int nb = n0 + k0 + bhalf * 16;
        #pragma unroll
        for (int j = 0; j < 16; ++j) {
            int n = nb + j;
            if (n > N_ - 1) n = N_ - 1;
            rb[j] = ent[(size_t)n * D_ + entcol];
        }
    };
    auto stage = [&](int bufbase) {
        #pragma unroll
        for (int c = 0; c < 2; ++c) {
            short8 hb, lb;
            #pragma unroll
            for (int j = 0; j < 8; ++j) {
                unsigned short h, lo;
                split_bf16(ra[c*8+j], h, lo);
                hb[j] = (short)h;
                lb[j] = (short)lo;
            }
            *reinterpret_cast<short8*>(&lds[bufbase + OLDS_A_HI + arow * APITCH + ahalf * 16 + c * 8]) = hb;
            *reinterpret_cast<short8*>(&lds[bufbase + OLDS_A_LO + arow * APITCH + ahalf * 16 + c * 8]) = lb;
        }
        #pragma unroll
        for (int c = 0; c < 2; ++c) {
            short8 hb, lb;
            #pragma unroll
            for (int j = 0; j < 8; ++j) {
                unsigned short h, lo;
                split_bf16(rb[c*8+j], h, lo);
                hb[j] = (short)h;
                lb[j] = (short)lo;
            }
            *reinterpret_cast<short8*>(&lds[bufbase + OLDS_B_HI + dcol * APITCH + bhalf * 16 + c * 8]) = hb;
            *reinterpret_cast<short8*>(&lds[bufbase + OLDS_B_LO + dcol * APITCH + bhalf * 16 + c * 8]) = lb;
        }
    };

    // prologue: stage tile 0, prefetch regs for tile 1
    loadA(0); loadB(0);
    stage(0);
    loadA(32); loadB(32);
    __syncthreads();

    for (int t = 0; t < 12; ++t) {
        const int base = (t & 1) * OG_BUF;
        const int nb2 = ((t + 1) & 1) * OG_BUF;
        if (t < 11) stage(nb2);                       // regs hold tile t+1
        if (t < 10) { loadA((t + 2) * 32); loadB((t + 2) * 32); }
        short8 ah[4], al[4], bh[4], bl[4];
        #pragma unroll
        for (int mi = 0; mi < 4; ++mi) {
            int r = m0w + mi * 16 + lm;
            ah[mi] = *reinterpret_cast<const short8*>(&lds[base + OLDS_A_HI + r * APITCH + kg * 8]);
            al[mi] = *reinterpret_cast<const short8*>(&lds[base + OLDS_A_LO + r * APITCH + kg * 8]);
        }
        #pragma unroll
        for (int nj = 0; nj < 4; ++nj) {
            int r = c0w + nj * 16 + lm;
            bh[nj] = *reinterpret_cast<const short8*>(&lds[base + OLDS_B_HI + r * APITCH + kg * 8]);
            bl[nj] = *reinterpret_cast<const short8*>(&lds[base + OLDS_B_LO + r * APITCH + kg * 8]);
        }
        #pragma unroll
        for (int mi = 0; mi < 4; ++mi)
            #pragma unroll
            for (int nj = 0; nj < 4; ++nj) {
                acc[mi][nj] = __builtin_amdgcn_mfma_f32_16x16x32_bf16(ah[mi], bh[nj], acc[mi][nj], 0, 0, 0);
                acc[mi][nj] = __builtin_amdgcn_mfma_f32_16x16x32_bf16(ah[mi], bl[nj], acc[mi][nj], 0, 0, 0);
                acc[mi][nj] = __builtin_amdgcn_mfma_f32_16x16x32_bf16(al[mi], bh[nj], acc[mi][nj], 0, 0, 0);
            }
        __syncthreads();
    }

    float* pbase = part + (size_t)chunk * 65536;
    #pragma unroll
    for (int nj = 0; nj < 4; ++nj) {
        int dcolo = d0 + c0w + nj * 16 + lm;
        #pragma unroll
        for (int mi = 0; mi < 4; ++mi) {
            int brow = m0w + mi * 16 + kg * 4;
            #pragma unroll
            for (int j = 0; j < 4; ++j)
                pbase[(size_t)(brow + j) * 512 + dcolo] = acc[mi][nj][j];
        }
    }
}

// ---------------- reduce partials + normalize by agg_sum ----------------
__global__ __launch_bounds__(256) void k_redout(const float* __restrict__ part,
                                                const float* __restrict__ stats,
                                                float* __restrict__ out) {
    int i = blockIdx.x * 256 + threadIdx.x;  // 0..65535
    int b = i >> 9;
    float s = 0.f;
    for (int c = 0; c < OCHUNK; ++c) s += part[(size_t)c * 65536 + i];
    out[i] = s / fmaxf(CLIPV, stats[ST_AGGSUM + b]);
}

extern "C" void kernel_launch(void* const* d_in, const int* in_sizes, int n_in,
                              void* d_out, int out_size, void* d_ws, size_t ws_size,
                              hipStream_t stream) {
    const float* ent = (const float*)d_in[0];
    const float* hv  = (const float*)d_in[1];
    const float* he  = (const float*)d_in[2];
    const float* pe  = (const float*)d_in[3];
    const float* ev  = (const float*)d_in[4];
    const int*   es  = (const int*)d_in[5];
    const int*   ed  = (const int*)d_in[6];
    float* out = (float*)d_out;
    float* ws = (float*)d_ws;

    unsigned short* tail_hi = (unsigned short*)(ws + OFF_TAIL);

    hipMemsetAsync(ws + OFF_SYM, 0, (size_t)AB_ * N_ * sizeof(float), stream);
    hipMemsetAsync(ws + OFF_STATS, 0, 2048 * sizeof(float), stream);

    k_tail<<<512, 256, 0, stream>>>(he, pe, tail_hi);
    k_scatter<<<AB_, 256, 0, stream>>>(hv, ev, es, ed, ws + OFF_SYM);
    k_score<<<782, 256, 0, stream>>>(ent, tail_hi, ws + OFF_SCORE, ws + OFF_STATS);
    k_symsum<<<AB_ * 4, 256, 0, stream>>>(ws + OFF_SYM, ws + OFF_STATS);
    k_enhagg<<<B_ * 4, 256, 0, stream>>>(ws + OFF_SCORE, ws + OFF_SYM, ws + OFF_STATS);
    k_outgemm<<<OCHUNK * 4, 256, 0, stream>>>(ent, ws + OFF_SCORE, ws + OFF_SYM);
    k_redout<<<256, 256, 0, stream>>>(ws + OFF_SYM, ws + OFF_STATS, out);
}